// Round 2
// baseline (209.717 us; speedup 1.0000x reference)
//
#include <hip/hip_runtime.h>
#include <cmath>

#define B_ 16384
#define S_ 512
#define P_ 1024
#define K_ 8
#define D_ 64
#define H_ 128
#define BT 8    // batch rows per block in the heavy kernel (16 KB LDS -> 8 blocks/CU)

// ---------------- Kernel A: sklproj[s][h] = dot(skl_emd[s,:], U[h,:]) ----------------
__global__ __launch_bounds__(128) void proj_skl_kernel(
    const float* __restrict__ skl_emd, const float* __restrict__ U,
    float* __restrict__ sklproj) {
  __shared__ float row[D_];
  const int s = blockIdx.x, h = threadIdx.x;
  if (h < D_) row[h] = skl_emd[s * D_ + h];
  __syncthreads();
  float acc = 0.f;
#pragma unroll
  for (int d = 0; d < D_; d++) acc += row[d] * U[h * D_ + d];
  sklproj[s * H_ + h] = acc;
}

// ---------------- Kernel B: att[p][k] = softmax_k( sum_h v[h]*tanh(projP[p][h]+sklproj[g[p][k]][h]) )
__global__ __launch_bounds__(128) void att_kernel(
    const float* __restrict__ plm_emd, const float* __restrict__ W,
    const float* __restrict__ vT, const float* __restrict__ sklproj,
    const int* __restrict__ gidx, float* __restrict__ att) {
  __shared__ float prow[D_];
  __shared__ float red[2][K_];
  const int p = blockIdx.x, h = threadIdx.x;
  if (h < D_) prow[h] = plm_emd[p * D_ + h];
  __syncthreads();
  float pp = 0.f;
#pragma unroll
  for (int d = 0; d < D_; d++) pp += prow[d] * W[h * D_ + d];
  const float v = vT[h];
  int g[K_];
#pragma unroll
  for (int k = 0; k < K_; k++) g[k] = gidx[p * K_ + k];
  float partial[K_];
#pragma unroll
  for (int k = 0; k < K_; k++) partial[k] = v * tanhf(pp + sklproj[g[k] * H_ + h]);
  // wave(64)-level reduce, then combine the 2 waves via LDS
#pragma unroll
  for (int off = 32; off >= 1; off >>= 1)
#pragma unroll
    for (int k = 0; k < K_; k++) partial[k] += __shfl_down(partial[k], off, 64);
  const int wave = h >> 6, lane = h & 63;
  if (lane == 0)
#pragma unroll
    for (int k = 0; k < K_; k++) red[wave][k] = partial[k];
  __syncthreads();
  if (h == 0) {
    float s[K_], m = -1e30f;
#pragma unroll
    for (int k = 0; k < K_; k++) { s[k] = red[0][k] + red[1][k]; m = fmaxf(m, s[k]); }
    float denom = 0.f;
#pragma unroll
    for (int k = 0; k < K_; k++) { s[k] = expf(s[k] - m); denom += s[k]; }
    const float inv = 1.f / denom;
#pragma unroll
    for (int k = 0; k < K_; k++) att[p * K_ + k] = s[k] * inv;
  }
}

// ---------------- Kernel C: out[b][p] = mask[b][p] * sum_k skl_pfc[b][g[p][k]] * att[p][k]
// BT=8 rows/block -> 16 KB LDS -> 8 blocks/CU; __launch_bounds__(256,8) caps VGPR at 64
// so occupancy is 32 waves/CU (was grid-capped at 16 with BT=16).
__global__ __launch_bounds__(256, 8) void out_kernel(
    const float* __restrict__ skl_pfc, const float* __restrict__ mask,
    const float* __restrict__ att, const int* __restrict__ gidx,
    float* __restrict__ out) {
  __shared__ float rows[BT][S_];  // 8 * 512 * 4B = 16 KB
  const int t = threadIdx.x;
  const int b0 = blockIdx.x * BT;

  // stage 8 skl_pfc rows, coalesced float4 (4096 floats / 256 threads = 4 f4/thread)
  const float4* __restrict__ src = (const float4*)(skl_pfc + (size_t)b0 * S_);
  float4* dst = (float4*)(&rows[0][0]);
#pragma unroll
  for (int i = 0; i < (BT * S_ / 4) / 256; i++) dst[t + i * 256] = src[t + i * 256];

  // per-thread att / idx tables (shared across all 8 b's): p = t + j*256
  float a[4][K_];
  int g[4][K_];
#pragma unroll
  for (int j = 0; j < 4; j++) {
    const int p = t + j * 256;
    const float4* ap = (const float4*)(att + p * K_);
    const int4* gp = (const int4*)(gidx + p * K_);
    float4 a0 = ap[0], a1 = ap[1];
    int4 g0 = gp[0], g1 = gp[1];
    a[j][0] = a0.x; a[j][1] = a0.y; a[j][2] = a0.z; a[j][3] = a0.w;
    a[j][4] = a1.x; a[j][5] = a1.y; a[j][6] = a1.z; a[j][7] = a1.w;
    g[j][0] = g0.x; g[j][1] = g0.y; g[j][2] = g0.z; g[j][3] = g0.w;
    g[j][4] = g1.x; g[j][5] = g1.y; g[j][6] = g1.z; g[j][7] = g1.w;
  }
  __syncthreads();

  for (int bb = 0; bb < BT; bb++) {
    const size_t rowoff = (size_t)(b0 + bb) * P_;
    const float* __restrict__ r = rows[bb];
    // hoist the streaming mask loads so they overlap the LDS gathers
    float m[4];
#pragma unroll
    for (int j = 0; j < 4; j++) m[j] = __builtin_nontemporal_load(mask + rowoff + t + j * 256);
#pragma unroll
    for (int j = 0; j < 4; j++) {
      const int p = t + j * 256;
      float acc = 0.f;
#pragma unroll
      for (int k = 0; k < K_; k++) acc += r[g[j][k]] * a[j][k];
      __builtin_nontemporal_store(acc * m[j], out + rowoff + p);
    }
  }
}

extern "C" void kernel_launch(void* const* d_in, const int* in_sizes, int n_in,
                              void* d_out, int out_size, void* d_ws, size_t ws_size,
                              hipStream_t stream) {
  const float* skl_pfc = (const float*)d_in[0];   // [B, S]
  const float* mask    = (const float*)d_in[1];   // [B, P]
  const float* skl_emd = (const float*)d_in[2];   // [S, D]
  const float* plm_emd = (const float*)d_in[3];   // [P, D]
  const float* W       = (const float*)d_in[4];   // [H, D]
  const float* U       = (const float*)d_in[5];   // [H, D]
  const float* vT      = (const float*)d_in[6];   // [1, H]
  const int*   gidx    = (const int*)d_in[7];     // [P, K]
  float* out = (float*)d_out;                     // [B, P]

  float* sklproj = (float*)d_ws;                  // S*H floats = 256 KB
  float* att     = sklproj + S_ * H_;             // P*K floats = 32 KB

  proj_skl_kernel<<<S_, 128, 0, stream>>>(skl_emd, U, sklproj);
  att_kernel<<<P_, 128, 0, stream>>>(plm_emd, W, vT, sklproj, gidx, att);
  out_kernel<<<B_ / BT, 256, 0, stream>>>(skl_pfc, mask, att, gidx, out);
}

// Round 3
// 177.536 us; speedup vs baseline: 1.1813x; 1.1813x over previous
//
#include <hip/hip_runtime.h>
#include <cmath>

#define B_ 16384
#define S_ 512
#define P_ 1024
#define K_ 8
#define D_ 64
#define H_ 128
#define BT 8     // batch rows per block
#define PAD 12   // LDS row stride in floats: 16B-aligned (48B), covers all bank groups

// ---------------- Kernel A: sklproj[s][h] = dot(skl_emd[s,:], U[h,:]) ----------------
__global__ __launch_bounds__(128) void proj_skl_kernel(
    const float* __restrict__ skl_emd, const float* __restrict__ U,
    float* __restrict__ sklproj) {
  __shared__ float row[D_];
  const int s = blockIdx.x, h = threadIdx.x;
  if (h < D_) row[h] = skl_emd[s * D_ + h];
  __syncthreads();
  float acc = 0.f;
#pragma unroll
  for (int d = 0; d < D_; d++) acc += row[d] * U[h * D_ + d];
  sklproj[s * H_ + h] = acc;
}

// ---------------- Kernel B: att[p][k] = softmax_k( sum_h v[h]*tanh(projP[p][h]+sklproj[g[p][k]][h]) )
__global__ __launch_bounds__(128) void att_kernel(
    const float* __restrict__ plm_emd, const float* __restrict__ W,
    const float* __restrict__ vT, const float* __restrict__ sklproj,
    const int* __restrict__ gidx, float* __restrict__ att) {
  __shared__ float prow[D_];
  __shared__ float red[2][K_];
  const int p = blockIdx.x, h = threadIdx.x;
  if (h < D_) prow[h] = plm_emd[p * D_ + h];
  __syncthreads();
  float pp = 0.f;
#pragma unroll
  for (int d = 0; d < D_; d++) pp += prow[d] * W[h * D_ + d];
  const float v = vT[h];
  int g[K_];
#pragma unroll
  for (int k = 0; k < K_; k++) g[k] = gidx[p * K_ + k];
  float partial[K_];
#pragma unroll
  for (int k = 0; k < K_; k++) partial[k] = v * tanhf(pp + sklproj[g[k] * H_ + h]);
#pragma unroll
  for (int off = 32; off >= 1; off >>= 1)
#pragma unroll
    for (int k = 0; k < K_; k++) partial[k] += __shfl_down(partial[k], off, 64);
  const int wave = h >> 6, lane = h & 63;
  if (lane == 0)
#pragma unroll
    for (int k = 0; k < K_; k++) red[wave][k] = partial[k];
  __syncthreads();
  if (h == 0) {
    float s[K_], m = -1e30f;
#pragma unroll
    for (int k = 0; k < K_; k++) { s[k] = red[0][k] + red[1][k]; m = fmaxf(m, s[k]); }
    float denom = 0.f;
#pragma unroll
    for (int k = 0; k < K_; k++) { s[k] = expf(s[k] - m); denom += s[k]; }
    const float inv = 1.f / denom;
#pragma unroll
    for (int k = 0; k < K_; k++) att[p * K_ + k] = s[k] * inv;
  }
}

// ---------------- Kernel C: out[b][p] = mask[b][p] * sum_k skl_pfc[b][g[p][k]] * att[p][k]
// LDS tile TRANSPOSED: rows_T[s][bb] so one ds_read_b128 gathers skill s for 4 batch
// rows at once -> 4x fewer LDS gather instructions than the b32 version.
// PAD=12 floats (48B): 16B-aligned rows, start-bank 12*g%32 covers all bank groups.
__global__ __launch_bounds__(256, 6) void out_kernel(
    const float* __restrict__ skl_pfc, const float* __restrict__ mask,
    const float* __restrict__ att, const int* __restrict__ gidx,
    float* __restrict__ out) {
  __shared__ __align__(16) float rows_T[S_][PAD];  // 512*12*4 = 24 KB -> 6 blocks/CU
  const int t = threadIdx.x;
  const int b0 = blockIdx.x * BT;

  // stage transposed: for s = t, t+256 read 8 batch values (coalesced across t per bb)
#pragma unroll
  for (int i = 0; i < S_ / 256; i++) {
    const int s = t + i * 256;
    float vals[BT];
#pragma unroll
    for (int bb = 0; bb < BT; bb++) vals[bb] = skl_pfc[(size_t)(b0 + bb) * S_ + s];
    float4* wp = (float4*)&rows_T[s][0];
    wp[0] = make_float4(vals[0], vals[1], vals[2], vals[3]);
    wp[1] = make_float4(vals[4], vals[5], vals[6], vals[7]);
  }
  __syncthreads();

  for (int j = 0; j < 4; j++) {
    const int p = t + j * 256;
    const float4* ap = (const float4*)(att + p * K_);
    const int4* gp = (const int4*)(gidx + p * K_);
    const float4 a0 = ap[0], a1 = ap[1];
    const int4 g0 = gp[0], g1 = gp[1];
    const float av[K_] = {a0.x, a0.y, a0.z, a0.w, a1.x, a1.y, a1.z, a1.w};
    const int gv[K_] = {g0.x, g0.y, g0.z, g0.w, g1.x, g1.y, g1.z, g1.w};
    float acc[BT] = {0.f, 0.f, 0.f, 0.f, 0.f, 0.f, 0.f, 0.f};
#pragma unroll
    for (int k = 0; k < K_; k++) {
      const float4* rp = (const float4*)&rows_T[gv[k]][0];
      const float4 v0 = rp[0];
      const float4 v1 = rp[1];
      const float a = av[k];
      acc[0] += v0.x * a; acc[1] += v0.y * a; acc[2] += v0.z * a; acc[3] += v0.w * a;
      acc[4] += v1.x * a; acc[5] += v1.y * a; acc[6] += v1.z * a; acc[7] += v1.w * a;
    }
#pragma unroll
    for (int bb = 0; bb < BT; bb++) {
      const size_t off = (size_t)(b0 + bb) * P_ + p;
      out[off] = acc[bb] * mask[off];
    }
  }
}

extern "C" void kernel_launch(void* const* d_in, const int* in_sizes, int n_in,
                              void* d_out, int out_size, void* d_ws, size_t ws_size,
                              hipStream_t stream) {
  const float* skl_pfc = (const float*)d_in[0];   // [B, S]
  const float* mask    = (const float*)d_in[1];   // [B, P]
  const float* skl_emd = (const float*)d_in[2];   // [S, D]
  const float* plm_emd = (const float*)d_in[3];   // [P, D]
  const float* W       = (const float*)d_in[4];   // [H, D]
  const float* U       = (const float*)d_in[5];   // [H, D]
  const float* vT      = (const float*)d_in[6];   // [1, H]
  const int*   gidx    = (const int*)d_in[7];     // [P, K]
  float* out = (float*)d_out;                     // [B, P]

  float* sklproj = (float*)d_ws;                  // S*H floats = 256 KB
  float* att     = sklproj + S_ * H_;             // P*K floats = 32 KB

  proj_skl_kernel<<<S_, 128, 0, stream>>>(skl_emd, U, sklproj);
  att_kernel<<<P_, 128, 0, stream>>>(plm_emd, W, vT, sklproj, gidx, att);
  out_kernel<<<B_ / BT, 256, 0, stream>>>(skl_pfc, mask, att, gidx, out);
}